// Round 13
// baseline (100.313 us; speedup 1.0000x reference)
//
#include <hip/hip_runtime.h>

#define BATCH  65536
#define NIN    9
#define NHID   100
#define TSTEPS 25
#define CHUNK  5
#define NW     8           // waves per block

typedef float v2f __attribute__((ext_vector_type(2)));

// Wave-uniform neuron mapping, 8-wave blocks: block = 64 batch elements
// (lane = batch elem), wave wq owns 13 or 12 neurons (13x4 + 12x4 = 100) ->
// weight reads are wave-uniform SGPR loads; hot loop has ZERO LDS traffic.
// f64 m-chain (tracks the f64 numpy arbiter), f32 fc2 acc (AGPR-resident is
// fine — round 12 proved v_fmac_f32 targets AGPRs with no move tax).
// ROUND-13: waves of work per SIMD 4 -> 8 at constant per-wave state; round
// 12 showed ~47% idle (latency-bound at 2-3 resident waves), so TLP is the
// lever. Cross-wave reduce single-buffered (20 KB), 2 barriers per chunk.
__global__ __launch_bounds__(512) void snn_kernel(
    const float* __restrict__ x,  const float* __restrict__ W1,
    const float* __restrict__ b1, const float* __restrict__ W2,
    const float* __restrict__ b2, float* __restrict__ out)
{
    __shared__ float sx[64 * NIN];           // 2.25 KB staged x rows
    __shared__ v2f   sacc[NW][CHUNK][64];    // 20 KB, single-buffered reduce

    const int tid  = threadIdx.x;
    const int lane = tid & 63;
    const int wq   = __builtin_amdgcn_readfirstlane(tid >> 6);
    const int b0   = blockIdx.x * 64;

    // cooperative coalesced x stage (64 rows x 9 f32)
    for (int i = tid; i < 64 * NIN; i += 512) sx[i] = x[(size_t)b0 * NIN + i];
    __syncthreads();

    // per-lane x row widened to f64
    double xv[NIN];
#pragma unroll
    for (int i = 0; i < NIN; ++i) xv[i] = (double)sx[lane * NIN + i];

    // per-step fc2 partial sums (f32; AGPR residency is free)
    float a0[TSTEPS], a1[TSTEPS];
#pragma unroll
    for (int t = 0; t < TSTEPS; ++t) { a0[t] = 0.f; a1[t] = 0.f; }

    // neuron split 13/13/13/13/12/12/12/12 (wave-uniform)
    const int cnt = (wq < 4) ? 13 : 12;
    const int h0  = (wq < 4) ? wq * 13 : 52 + (wq - 4) * 12;

#pragma unroll 1
    for (int j = 0; j < cnt; ++j) {
        const int h = h0 + j;                  // wave-uniform
        double c = 0.0;
#pragma unroll
        for (int i = 0; i < NIN; ++i)
            c += (double)W1[h * NIN + i] * xv[i];   // s_load weights
        c += (double)b1[h];
        double c1 = c - 1.0;                   // addend when prev step spiked
        float w0 = W2[h], w1 = W2[NHID + h];   // uniform scalar loads

        double m = 0.0;
        bool s = false;                        // spike(t-1) == reset(t)
#pragma unroll
        for (int t = 0; t < TSTEPS; ++t) {
            m = 0.95 * m + (s ? c1 : c);       // f64 leaky integrate + reset
            s = (m > 1.0);                     // f64 spike decision
            float d = s ? 1.f : 0.f;
            a0[t] = fmaf(d, w0, a0[t]);
            a1[t] = fmaf(d, w1, a1[t]);
        }
    }

    // chunked cross-wave reduce + mem2 (wave 0). Single-buffered: barrier
    // after writes (visibility), barrier after wq0's reads (reuse safety).
    // All acc indices compile-time constants (round-9 lesson).
    double m20 = 0.0, m21 = 0.0;
    double bb0 = (double)b2[0], bb1 = (double)b2[1];

#pragma unroll
    for (int k = 0; k < TSTEPS / CHUNK; ++k) {
#pragma unroll
        for (int u = 0; u < CHUNK; ++u)
            sacc[wq][u][lane] = (v2f){a0[k * CHUNK + u], a1[k * CHUNK + u]};
        __syncthreads();
        if (wq == 0) {
#pragma unroll
            for (int u = 0; u < CHUNK; ++u) {
                const int t = k * CHUNK + u;
                v2f p0 = sacc[0][u][lane];
                v2f p1 = sacc[1][u][lane];
                v2f p2 = sacc[2][u][lane];
                v2f p3 = sacc[3][u][lane];
                v2f p4 = sacc[4][u][lane];
                v2f p5 = sacc[5][u][lane];
                v2f p6 = sacc[6][u][lane];
                v2f p7 = sacc[7][u][lane];
                v2f sum = ((p0 + p1) + (p2 + p3)) + ((p4 + p5) + (p6 + p7));
                double r0 = (m20 > 1.0) ? 1.0 : 0.0;
                double r1 = (m21 > 1.0) ? 1.0 : 0.0;
                m20 = 0.95 * m20 + ((double)sum[0] + bb0) - r0;
                m21 = 0.95 * m21 + ((double)sum[1] + bb1) - r1;
                *(float2*)(out + ((size_t)t * BATCH + b0 + lane) * 2) =
                    make_float2((float)m20, (float)m21);
            }
        }
        __syncthreads();   // chunk k fully consumed before chunk k+1 writes
    }
}

extern "C" void kernel_launch(void* const* d_in, const int* in_sizes, int n_in,
                              void* d_out, int out_size, void* d_ws, size_t ws_size,
                              hipStream_t stream) {
    const float* x  = (const float*)d_in[0];
    const float* W1 = (const float*)d_in[1];
    const float* b1 = (const float*)d_in[2];
    const float* W2 = (const float*)d_in[3];
    const float* b2 = (const float*)d_in[4];
    float* out = (float*)d_out;

    dim3 grid(BATCH / 64), block(512);
    hipLaunchKernelGGL(snn_kernel, grid, block, 0, stream, x, W1, b1, W2, b2, out);
}

// Round 14
// 98.746 us; speedup vs baseline: 1.0159x; 1.0159x over previous
//
#include <hip/hip_runtime.h>

#define BATCH   65536
#define NIN     9
#define NHID    100
#define TSTEPS  25
#define CHUNK   5
#define NW      4
#define W1S     10          // padded f64 row stride (80 B, rows 16B-aligned)

typedef float v2f __attribute__((ext_vector_type(2)));

// Wave-uniform neuron mapping (block = 64 batch elems, wave wq owns neurons
// [25wq,25wq+25)). ROUND-14: W1/b1 staged as f64 in LDS (kills 9 cvt_f64 per
// neuron) and the weight row for neuron j+1 is prefetched into a ping-pong
// register buffer BEFORE neuron j's ~450-cyc t-loop — the in-order lgkmcnt
// drain that serialized every j-iteration (~5k cyc/wave, the flat-44us/62%%
// plateau of rounds 7-13) is hidden under compute. Hot loop is DS-only (no
// SMEM mixing in lgkmcnt). f64 m-chain unchanged -> bit-identical output.
__global__ __launch_bounds__(256) void snn_kernel(
    const float* __restrict__ x,  const float* __restrict__ W1,
    const float* __restrict__ b1, const float* __restrict__ W2,
    const float* __restrict__ b2, float* __restrict__ out)
{
    __shared__ double sxd[64 * NIN];            // 4.6 KB x rows, f64
    __shared__ double sW1d[NHID * W1S];         // 8.0 KB W1, f64, padded rows
    __shared__ double sb1d[NHID];               // 0.8 KB
    __shared__ float  sW2[2 * NHID];            // 0.8 KB
    __shared__ v2f    sacc[2][NW][CHUNK][64];   // 20.5 KB double-buffered reduce

    const int tid  = threadIdx.x;
    const int lane = tid & 63;
    const int wq   = __builtin_amdgcn_readfirstlane(tid >> 6);
    const int b0   = blockIdx.x * 64;

    // staging (coalesced global reads, one-time cvts)
    for (int i = tid; i < 64 * NIN; i += 256)
        sxd[i] = (double)x[(size_t)b0 * NIN + i];
    for (int i = tid; i < NHID * NIN; i += 256)
        sW1d[(i / NIN) * W1S + (i % NIN)] = (double)W1[i];
    if (tid < NHID)     sb1d[tid] = (double)b1[tid];
    if (tid < 2 * NHID) sW2[tid]  = W2[tid];
    __syncthreads();

    // per-lane x row (18 VGPRs, one-time LDS read)
    double xv[NIN];
#pragma unroll
    for (int i = 0; i < NIN; ++i) xv[i] = sxd[lane * NIN + i];

    // per-step fc2 partial sums (AGPR-resident is fine — round 12)
    float a0[TSTEPS], a1[TSTEPS];
#pragma unroll
    for (int t = 0; t < TSTEPS; ++t) { a0[t] = 0.f; a1[t] = 0.f; }

    const int h0 = wq * 25;

    // one neuron's full LIF + fc2 accumulate (t-loop unrolled; acc indices const)
    auto proc = [&](const double* R, double cb, float w0, float w1) {
        double c = 0.0;
#pragma unroll
        for (int i = 0; i < NIN; ++i) c += R[i] * xv[i];
        c += cb;
        double c1 = c - 1.0;
        double m = 0.0;
        bool s = false;                        // spike(t-1) == reset(t)
#pragma unroll
        for (int t = 0; t < TSTEPS; ++t) {
            m = 0.95 * m + (s ? c1 : c);       // f64 leaky integrate + reset
            s = (m > 1.0);                     // f64 spike decision
            float d = s ? 1.f : 0.f;
            a0[t] = fmaf(d, w0, a0[t]);
            a1[t] = fmaf(d, w1, a1[t]);
        }
    };

    // ping-pong row buffers: B's reads issue before proc(A)'s t-loop
    double A[NIN], B[NIN];
#pragma unroll
    for (int i = 0; i < NIN; ++i) A[i] = sW1d[h0 * W1S + i];

#pragma unroll 1
    for (int jj = 0; jj < 24; jj += 2) {
        const int hA = h0 + jj, hB = hA + 1;
        // uniform bias/weight reads first (their in-order waits are ~free)
        double bA = sb1d[hA], bB = sb1d[hB];
        float wA0 = sW2[hA], wA1 = sW2[NHID + hA];
        float wB0 = sW2[hB], wB1 = sW2[NHID + hB];
        // prefetch row hB — latency hidden by proc(A)
#pragma unroll
        for (int i = 0; i < NIN; ++i) B[i] = sW1d[hB * W1S + i];
        proc(A, bA, wA0, wA1);
        // prefetch row hA+2 (max 24, in range) — hidden by proc(B)
#pragma unroll
        for (int i = 0; i < NIN; ++i) A[i] = sW1d[(hA + 2) * W1S + i];
        proc(B, bB, wB0, wB1);
    }
    // tail neuron j = 24 (A holds row h0+24)
    {
        const int h = h0 + 24;
        proc(A, sb1d[h], sW2[h], sW2[NHID + h]);
    }

    // chunked cross-wave reduce + mem2 (wave 0), double-buffered LDS.
    // All acc indices compile-time constants (round-9 lesson).
    double m20 = 0.0, m21 = 0.0;
    double bb0 = (double)b2[0], bb1 = (double)b2[1];

#pragma unroll
    for (int k = 0; k < TSTEPS / CHUNK; ++k) {
#pragma unroll
        for (int u = 0; u < CHUNK; ++u)
            sacc[k & 1][wq][u][lane] = (v2f){a0[k * CHUNK + u], a1[k * CHUNK + u]};
        __syncthreads();
        // wave0 reads buf[k&1] before the NEXT barrier; other waves can't
        // overwrite buf[k&1] until chunk k+2's writes, behind that barrier.
        if (wq == 0) {
#pragma unroll
            for (int u = 0; u < CHUNK; ++u) {
                const int t = k * CHUNK + u;
                v2f q0 = sacc[k & 1][0][u][lane];
                v2f q1 = sacc[k & 1][1][u][lane];
                v2f q2 = sacc[k & 1][2][u][lane];
                v2f q3 = sacc[k & 1][3][u][lane];
                v2f sum = (q0 + q1) + (q2 + q3);   // butterfly bracketing
                double r0 = (m20 > 1.0) ? 1.0 : 0.0;
                double r1 = (m21 > 1.0) ? 1.0 : 0.0;
                m20 = 0.95 * m20 + ((double)sum[0] + bb0) - r0;
                m21 = 0.95 * m21 + ((double)sum[1] + bb1) - r1;
                *(float2*)(out + ((size_t)t * BATCH + b0 + lane) * 2) =
                    make_float2((float)m20, (float)m21);
            }
        }
    }
}

extern "C" void kernel_launch(void* const* d_in, const int* in_sizes, int n_in,
                              void* d_out, int out_size, void* d_ws, size_t ws_size,
                              hipStream_t stream) {
    const float* x  = (const float*)d_in[0];
    const float* W1 = (const float*)d_in[1];
    const float* b1 = (const float*)d_in[2];
    const float* W2 = (const float*)d_in[3];
    const float* b2 = (const float*)d_in[4];
    float* out = (float*)d_out;

    dim3 grid(BATCH / 64), block(256);
    hipLaunchKernelGGL(snn_kernel, grid, block, 0, stream, x, W1, b1, W2, b2, out);
}